// Round 11
// baseline (61.703 us; speedup 1.0000x reference)
//
#include <hip/hip_runtime.h>
#include <math.h>

#define N 64
#define F 64
#define W 40
#define D 512
#define LSM 9.0f
#define LLSE 6.0f
#define MARG 0.2f

typedef _Float16 f16x8 __attribute__((ext_vector_type(8)));
typedef _Float16 f16x4 __attribute__((ext_vector_type(4)));
typedef float f32x4 __attribute__((ext_vector_type(4)));

__device__ inline void gll16(const void* g, void* l) {
  __builtin_amdgcn_global_load_lds(
      (const __attribute__((address_space(1))) unsigned int*)g,
      (__attribute__((address_space(3))) unsigned int*)l, 16, 0, 0);
}

// layouts (halves), K-chunked (8 chunks of 64) + XOR swizzle baked in:
//  img_h per i: [ch8][f64][64],  halfidx ^ ((f&7)<<3)               (32768)
//  cap_h per j: [ch8][w48][64], halfidx ^ ((w&7)<<3), rows 40..47=0 (24576)
//  G_h  per j: [w48][64] linear, zero outside 40 rows/48 cols       (3072)
//  A_g  per pair (j*64+i): [40][64] fp16, fully masked              (2560)

// ---------------- k_pre: grid 320 x 512 ----------------
__global__ __launch_bounds__(512) void k_pre(
    const float* __restrict__ img, const float* __restrict__ cap,
    _Float16* __restrict__ img_h, _Float16* __restrict__ cap_h,
    _Float16* __restrict__ G_h, float* __restrict__ n1) {
  __shared__ __align__(16) _Float16 capT[4 * 48 * 128];  // 48 KB (cap blocks only)
  int t = threadIdx.x;
  int b = blockIdx.x;
  if (b < 256) {
    int i = b >> 2;
    int f = ((b & 3) << 4) + (t >> 5);
    int q = t & 31;  // 16 halves per thread
    const float* row = img + ((size_t)i * F + f) * D + q * 16;
    _Float16* dsti = img_h + (size_t)i * 32768;
    int fsw = (f & 7) << 3;
    float s = 0.f;
    int d0 = q * 16;
    int ch = d0 >> 6, din = d0 & 63;
#pragma unroll
    for (int k = 0; k < 2; ++k) {
      float4 u = *(const float4*)(row + k * 8);
      float4 v = *(const float4*)(row + k * 8 + 4);
      s += u.x * u.x + u.y * u.y + u.z * u.z + u.w * u.w;
      s += v.x * v.x + v.y * v.y + v.z * v.z + v.w * v.w;
      f16x8 h;
      h[0] = (_Float16)u.x; h[1] = (_Float16)u.y; h[2] = (_Float16)u.z; h[3] = (_Float16)u.w;
      h[4] = (_Float16)v.x; h[5] = (_Float16)v.y; h[6] = (_Float16)v.z; h[7] = (_Float16)v.w;
      *(f16x8*)(dsti + ch * 4096 + f * 64 + ((din + k * 8) ^ fsw)) = h;
    }
    s += __shfl_xor(s, 1);
    s += __shfl_xor(s, 2);
    s += __shfl_xor(s, 4);
    s += __shfl_xor(s, 8);
    s += __shfl_xor(s, 16);
    if (q == 0) n1[i * F + f] = sqrtf(s);
  } else {
    int j = b - 256;
    int lane = t & 63, wv = t >> 6;
    const float* src = cap + (size_t)j * W * D;
    _Float16* dst = cap_h + (size_t)j * 24576;
#pragma unroll
    for (int k = 0; k < 6; ++k) {
      int slot = t + k * 512;  // 48 rows x 64 col-chunks
      int w = slot >> 6, d = (slot & 63) * 8;
      float4 u = {0.f, 0.f, 0.f, 0.f}, v = {0.f, 0.f, 0.f, 0.f};
      if (w < W) {
        u = *(const float4*)(src + (size_t)w * D + d);
        v = *(const float4*)(src + (size_t)w * D + d + 4);
      }
      f16x8 h;
      h[0] = (_Float16)u.x; h[1] = (_Float16)u.y; h[2] = (_Float16)u.z; h[3] = (_Float16)u.w;
      h[4] = (_Float16)v.x; h[5] = (_Float16)v.y; h[6] = (_Float16)v.z; h[7] = (_Float16)v.w;
      int wsw = (w & 7) << 3;
      int ch2 = d >> 6, din2 = d & 63;
      *(f16x8*)(dst + ch2 * 3072 + w * 64 + (din2 ^ wsw)) = h;
      int chO = d >> 7, dinO = d & 127;
      *(f16x8*)(capT + chO * 6144 + w * 128 + (dinO ^ wsw)) = h;
    }
    __syncthreads();
    int lane2 = t & 63;
    int rlo = lane2 & 15, hi = lane2 >> 4;
    int koff = hi * 8, sw = (rlo & 7) << 3;
    _Float16* gb = G_h + (size_t)j * 3072;
    for (int tile = wv; tile < 9; tile += 8) {
      int mt = tile / 3, kt = tile % 3;
      f32x4 acc = (f32x4)0.f;
#pragma unroll
      for (int ks = 0; ks < 16; ++ks) {
        int kk = ks * 32 + koff;
        int ch = kk >> 7, din = (kk & 127) ^ sw;
        f16x8 af = *(const f16x8*)(capT + ch * 6144 + (mt * 16 + rlo) * 128 + din);
        f16x8 bf = *(const f16x8*)(capT + ch * 6144 + (kt * 16 + rlo) * 128 + din);
        acc = __builtin_amdgcn_mfma_f32_16x16x32_f16(af, bf, acc, 0, 0, 0);
      }
#pragma unroll
      for (int r = 0; r < 4; ++r) {
        int w = mt * 16 + hi * 4 + r, k = kt * 16 + rlo;
        float val = (w < W && k < W) ? acc[r] : 0.f;
        gb[w * 64 + k] = (_Float16)val;
      }
    }
    // zero G cols 48..63 (K-tail read against E garbage -> must be 0)
    if (t < 96) {
      int w = t >> 1, c8 = 48 + (t & 1) * 8;
      *(f16x8*)(gb + w * 64 + c8) = (f16x8)(_Float16)0.f;
    }
  }
}

// ---------------- k_gemm: 512 blocks x 512 thr; block = 4j x 2i = 8 pairs ----------------
// R10's proven A-phase; epilogue replaced by masked fp16 A stores.
__global__ __launch_bounds__(512, 4) void k_gemm(
    const _Float16* __restrict__ img_h, const _Float16* __restrict__ cap_h,
    const int* __restrict__ imgL, const int* __restrict__ capL,
    _Float16* __restrict__ A_g) {
  __shared__ __align__(16) char buf[81920];  // 2 x 40KB chunk dbuf

  int t = threadIdx.x;
  int lane = t & 63, wv = t >> 6;
  int rlo = lane & 15, hi = lane >> 4;
  int koff = hi * 8;
  int sw = (rlo & 7) << 3;

  int bid = blockIdx.x;
  int xcd = bid & 7, s0 = bid >> 3;
  int jloc = wv & 3, iloc = wv >> 2;
  int i = (xcd & 3) * 16 + (s0 & 7) * 2 + iloc;
  int j = (xcd >> 2) * 32 + (s0 >> 3) * 4 + jloc;

  int iL = imgL[i], cL = capL[j];

  const char* capb = (const char*)cap_h + (size_t)(j - jloc) * 49152;
  const char* imgb = (const char*)img_h + (size_t)(i - iloc) * 65536;

  const char* bsrc[5];
  int cstr[5], mdst[5];
#pragma unroll
  for (int s = 0; s < 5; ++s) {
    int m = s * 8 + wv;
    if (m < 24) {
      bsrc[s] = capb + (m / 6) * 49152 + (m % 6) * 1024 + lane * 16;
      cstr[s] = 6144;
    } else {
      int e = m - 24;
      bsrc[s] = imgb + (e >> 3) * 65536 + (e & 7) * 1024 + lane * 16;
      cstr[s] = 8192;
    }
    mdst[s] = m * 1024;
  }

  f32x4 acc[3][4];
#pragma unroll
  for (int mt = 0; mt < 3; ++mt)
#pragma unroll
    for (int nt = 0; nt < 4; ++nt) acc[mt][nt] = (f32x4)0.f;

#pragma unroll
  for (int s = 0; s < 5; ++s) gll16(bsrc[s], buf + mdst[s]);

#pragma unroll
  for (int c = 0; c < 8; ++c) {
    if (c < 7) {
      char* db = buf + ((c + 1) & 1) * 40960;
#pragma unroll
      for (int s = 0; s < 5; ++s) gll16(bsrc[s] + (c + 1) * cstr[s], db + mdst[s]);
      asm volatile("s_waitcnt vmcnt(5)" ::: "memory");
    } else {
      asm volatile("s_waitcnt vmcnt(0)" ::: "memory");
    }
    __builtin_amdgcn_s_barrier();
    __builtin_amdgcn_sched_barrier(0);
    const char* cb = buf + (c & 1) * 40960;
    const _Float16* myCap = (const _Float16*)cb + jloc * 3072;
    const _Float16* myImg = (const _Float16*)(cb + 24576) + iloc * 4096;
#pragma unroll
    for (int ks = 0; ks < 2; ++ks) {
      int col = (ks * 32 + koff) ^ sw;
      f16x8 af[3], bf[4];
#pragma unroll
      for (int mt = 0; mt < 3; ++mt) af[mt] = *(const f16x8*)(myCap + (mt * 16 + rlo) * 64 + col);
#pragma unroll
      for (int nt = 0; nt < 4; ++nt) bf[nt] = *(const f16x8*)(myImg + (nt * 16 + rlo) * 64 + col);
#pragma unroll
      for (int mt = 0; mt < 3; ++mt)
#pragma unroll
        for (int nt = 0; nt < 4; ++nt)
          acc[mt][nt] = __builtin_amdgcn_mfma_f32_16x16x32_f16(af[mt], bf[nt], acc[mt][nt], 0, 0, 0);
    }
    __builtin_amdgcn_sched_barrier(0);
    __builtin_amdgcn_s_barrier();
  }

  // store masked A[pair][40][64] fp16
  _Float16* Ag = A_g + (size_t)((j << 6) + i) * 2560;
#pragma unroll
  for (int mt = 0; mt < 3; ++mt)
#pragma unroll
    for (int r = 0; r < 4; ++r) {
      int w = mt * 16 + hi * 4 + r;
      if (w < W) {
#pragma unroll
        for (int nt = 0; nt < 4; ++nt) {
          int f = nt * 16 + rlo;
          float v = (w < cL && f < iL) ? acc[mt][nt][r] : 0.f;
          Ag[w * 64 + f] = (_Float16)v;
        }
      }
    }
}

// ---------------- k_epi: 4096 blocks x 256 thr; block = one (i,j) pair ----------------
// High-occupancy epilogue: ~16 KB LDS, low VGPR -> 8 blocks/CU (32 waves/CU).
__global__ __launch_bounds__(256, 8) void k_epi(
    const _Float16* __restrict__ A_g, const _Float16* __restrict__ G_h,
    const int* __restrict__ imgL, const int* __restrict__ capL,
    const float* __restrict__ n1g, float* __restrict__ S) {
  __shared__ __align__(16) _Float16 Al[40 * 72];  // 5760 B (stride 72: 16B-aligned rows)
  __shared__ __align__(16) _Float16 Es[64 * 72];  // 9216 B
  __shared__ float rinv_s[W];
  __shared__ float numu[F];
  __shared__ float red[4];

  int t = threadIdx.x;
  int lane = t & 63, wv = t >> 6;
  int rlo = lane & 15, hi = lane >> 4;
  int koff = hi * 8;

  int bid = blockIdx.x;
  int j = bid >> 6, i = bid & 63;
  int iL = imgL[i], cL = capL[j];

  // zero Es fully (cols 40..71 are K-tail / pad read by MFMA -> must be finite 0)
  for (int k = t; k < 576; k += 256) ((f16x8*)Es)[k] = (f16x8)(_Float16)0.f;

  // load A[40][64] -> Al[40][72] (coalesced global, 16 halves/thread)
  if (t < 160) {
    const _Float16* src = A_g + (size_t)bid * 2560 + t * 16;
    f16x8 a0 = *(const f16x8*)src;
    f16x8 a1 = *(const f16x8*)(src + 8);
    int row = t >> 2, colb = (t & 3) * 16;
    *(f16x8*)(Al + row * 72 + colb) = a0;
    *(f16x8*)(Al + row * 72 + colb + 8) = a1;
  }
  __syncthreads();

  // rnorm per w (A pre-masked -> zeros contribute 0)
  if (t < 160) {
    int w = t >> 2, q = t & 3;
    const _Float16* p = Al + w * 72 + q * 16;
    float s = 0.f;
#pragma unroll
    for (int k = 0; k < 2; ++k) {
      f16x8 h = *(const f16x8*)(p + k * 8);
#pragma unroll
      for (int e = 0; e < 8; ++e) {
        float a = (float)h[e];
        float l = a > 0.f ? a : 0.1f * a;
        s += l * l;
      }
    }
    s += __shfl_xor(s, 1);
    s += __shfl_xor(s, 2);
    if (q == 0) rinv_s[w] = 1.f / (sqrtf(s) + 1e-8f);
  }
  __syncthreads();

  // softmax (unnormalized, logits in [-9,9]) + numerator; E -> LDS [f][w]
  {
    int c = t & 3, f = t >> 2;
    float sn = 0.f;
#pragma unroll
    for (int k = 0; k < 10; ++k) {
      int w = c + 4 * k;
      float a = (float)Al[w * 72 + f];
      float l = a > 0.f ? a : 0.1f * a;
      float e = (w < cL) ? __expf(LSM * l * rinv_s[w]) : 0.f;
      sn = fmaf(e, a, sn);
      Es[f * 72 + w] = (_Float16)e;
    }
    sn += __shfl_xor(sn, 1);
    sn += __shfl_xor(sn, 2);
    if (c == 0) numu[f] = sn;
  }
  __syncthreads();

  // P = E*G (K=64; E cols>=40 zero x G; G rows 40..47 zero); wave wv owns f rows wv*16..+15
  int fr = wv * 16 + rlo;
  const _Float16* gB = G_h + (size_t)j * 3072;
  f32x4 P[3];
#pragma unroll
  for (int ntl = 0; ntl < 3; ++ntl) P[ntl] = (f32x4)0.f;
#pragma unroll
  for (int ks2 = 0; ks2 < 2; ++ks2) {
    int kk = ks2 * 32 + koff;
    f16x8 ea = *(const f16x8*)(Es + fr * 72 + kk);
#pragma unroll
    for (int ntl = 0; ntl < 3; ++ntl) {
      f16x8 gb = *(const f16x8*)(gB + (ntl * 16 + rlo) * 64 + kk);
      P[ntl] = __builtin_amdgcn_mfma_f32_16x16x32_f16(ea, gb, P[ntl], 0, 0, 0);
    }
  }

  // n2^2 per f; sim; LSE partials
  float ef = 0.f;
#pragma unroll
  for (int rr = 0; rr < 4; ++rr) {
    int fm = wv * 16 + hi * 4 + rr;
    float n2s = 0.f;
#pragma unroll
    for (int ntl = 0; ntl < 3; ++ntl) {
      float evv = (float)Es[fm * 72 + ntl * 16 + rlo];
      n2s = fmaf(P[ntl][rr], evv, n2s);
    }
#pragma unroll
    for (int d = 1; d < 16; d <<= 1) n2s += __shfl_xor(n2s, d);
    float nm = numu[fm];
    float n1v = n1g[i * F + fm];
    float denom = n1v * sqrtf(fmaxf(n2s, 0.f));
    float sim = nm / fmaxf(denom, 1e-20f);
    ef += (fm < iL) ? __expf(LLSE * sim) : 0.f;
  }
  float val = (rlo == 0) ? ef : 0.f;
#pragma unroll
  for (int d = 1; d < 64; d <<= 1) val += __shfl_xor(val, d);
  if (lane == 0) red[wv] = val;
  __syncthreads();
  if (t == 0) S[(j << 6) + i] = __logf(red[0] + red[1] + red[2] + red[3]) * (1.f / LLSE);
}

// ---------------- k_loss ----------------
__global__ void k_loss(const float* __restrict__ S, float* __restrict__ out) {
  __shared__ float red[128];
  int t = threadIdx.x;
  float m = -1e30f;
  if (t < 64) {
    int a = t;
    float da = S[a * N + a];
    for (int b = 0; b < N; ++b)
      if (b != a) m = fmaxf(m, MARG + S[a * N + b] - da);
  } else {
    int b = t - 64;
    float db = S[b * N + b];
    for (int a = 0; a < N; ++a)
      if (a != b) m = fmaxf(m, MARG + S[a * N + b] - db);
  }
  red[t] = fmaxf(m, 0.f);
  __syncthreads();
  if (t < 64) {
    float v = red[t] + red[t + 64];
#pragma unroll
    for (int off = 1; off < 64; off <<= 1) v += __shfl_xor(v, off);
    if (t == 0) *out = v;
  }
}

extern "C" void kernel_launch(void* const* d_in, const int* in_sizes, int n_in,
                              void* d_out, int out_size, void* d_ws, size_t ws_size,
                              hipStream_t stream) {
  const float* img = (const float*)d_in[0];
  const float* cap = (const float*)d_in[1];
  const int* imgL = (const int*)d_in[2];
  const int* capL = (const int*)d_in[3];

  char* wsb = (char*)d_ws;
  float* n1 = (float*)wsb;                                       // 16 KB
  float* S = (float*)(wsb + 16384);                              // 16 KB
  _Float16* img_h = (_Float16*)(wsb + 32768);                    // 4 MB
  _Float16* cap_h = (_Float16*)(wsb + 32768 + 4194304);          // 3 MB
  _Float16* G_h = (_Float16*)(wsb + 32768 + 4194304 + 3145728);  // 384 KB
  _Float16* A_g = (_Float16*)(wsb + 32768 + 4194304 + 3145728 + 393216);  // 20 MB

  k_pre<<<320, 512, 0, stream>>>(img, cap, img_h, cap_h, G_h, n1);
  k_gemm<<<512, 512, 0, stream>>>(img_h, cap_h, imgL, capL, A_g);
  k_epi<<<4096, 256, 0, stream>>>(A_g, G_h, imgL, capL, n1, S);
  k_loss<<<1, 128, 0, stream>>>(S, (float*)d_out);
}

// Round 12
// 54.072 us; speedup vs baseline: 1.1411x; 1.1411x over previous
//
#include <hip/hip_runtime.h>
#include <math.h>

#define N 64
#define F 64
#define W 40
#define D 512
#define LSM 9.0f
#define LLSE 6.0f
#define MARG 0.2f
#define ESTR 56  // Es row stride in halves

typedef _Float16 f16x8 __attribute__((ext_vector_type(8)));
typedef _Float16 f16x4 __attribute__((ext_vector_type(4)));
typedef float f32x4 __attribute__((ext_vector_type(4)));

__device__ inline void gll16(const void* g, void* l) {
  __builtin_amdgcn_global_load_lds(
      (const __attribute__((address_space(1))) unsigned int*)g,
      (__attribute__((address_space(3))) unsigned int*)l, 16, 0, 0);
}

// layouts (halves), K-chunked (8 chunks of 64) + XOR swizzle baked in:
//  img_h per i: [ch8][f64][64],  halfidx ^ ((f&7)<<3)               (32768)
//  cap_h per j: [ch8][w48][64], halfidx ^ ((w&7)<<3), rows 40..47=0 (24576)
//  G_h  per j: [w48][64] linear, zero outside 40 rows/48 cols       (3072)

// ---------------- k_pre: grid 320 x 512 (unchanged, proven) ----------------
__global__ __launch_bounds__(512) void k_pre(
    const float* __restrict__ img, const float* __restrict__ cap,
    _Float16* __restrict__ img_h, _Float16* __restrict__ cap_h,
    _Float16* __restrict__ G_h, float* __restrict__ n1) {
  __shared__ __align__(16) _Float16 capT[4 * 48 * 128];  // 48 KB (cap blocks only)
  int t = threadIdx.x;
  int b = blockIdx.x;
  if (b < 256) {
    int i = b >> 2;
    int f = ((b & 3) << 4) + (t >> 5);
    int q = t & 31;  // 16 halves per thread
    const float* row = img + ((size_t)i * F + f) * D + q * 16;
    _Float16* dsti = img_h + (size_t)i * 32768;
    int fsw = (f & 7) << 3;
    float s = 0.f;
    int d0 = q * 16;
    int ch = d0 >> 6, din = d0 & 63;
#pragma unroll
    for (int k = 0; k < 2; ++k) {
      float4 u = *(const float4*)(row + k * 8);
      float4 v = *(const float4*)(row + k * 8 + 4);
      s += u.x * u.x + u.y * u.y + u.z * u.z + u.w * u.w;
      s += v.x * v.x + v.y * v.y + v.z * v.z + v.w * v.w;
      f16x8 h;
      h[0] = (_Float16)u.x; h[1] = (_Float16)u.y; h[2] = (_Float16)u.z; h[3] = (_Float16)u.w;
      h[4] = (_Float16)v.x; h[5] = (_Float16)v.y; h[6] = (_Float16)v.z; h[7] = (_Float16)v.w;
      *(f16x8*)(dsti + ch * 4096 + f * 64 + ((din + k * 8) ^ fsw)) = h;
    }
    s += __shfl_xor(s, 1);
    s += __shfl_xor(s, 2);
    s += __shfl_xor(s, 4);
    s += __shfl_xor(s, 8);
    s += __shfl_xor(s, 16);
    if (q == 0) n1[i * F + f] = sqrtf(s);
  } else {
    int j = b - 256;
    int lane = t & 63, wv = t >> 6;
    const float* src = cap + (size_t)j * W * D;
    _Float16* dst = cap_h + (size_t)j * 24576;
#pragma unroll
    for (int k = 0; k < 6; ++k) {
      int slot = t + k * 512;  // 48 rows x 64 col-chunks
      int w = slot >> 6, d = (slot & 63) * 8;
      float4 u = {0.f, 0.f, 0.f, 0.f}, v = {0.f, 0.f, 0.f, 0.f};
      if (w < W) {
        u = *(const float4*)(src + (size_t)w * D + d);
        v = *(const float4*)(src + (size_t)w * D + d + 4);
      }
      f16x8 h;
      h[0] = (_Float16)u.x; h[1] = (_Float16)u.y; h[2] = (_Float16)u.z; h[3] = (_Float16)u.w;
      h[4] = (_Float16)v.x; h[5] = (_Float16)v.y; h[6] = (_Float16)v.z; h[7] = (_Float16)v.w;
      int wsw = (w & 7) << 3;
      int ch2 = d >> 6, din2 = d & 63;
      *(f16x8*)(dst + ch2 * 3072 + w * 64 + (din2 ^ wsw)) = h;
      int chO = d >> 7, dinO = d & 127;
      *(f16x8*)(capT + chO * 6144 + w * 128 + (dinO ^ wsw)) = h;
    }
    __syncthreads();
    int lane2 = t & 63;
    int rlo = lane2 & 15, hi = lane2 >> 4;
    int koff = hi * 8, sw = (rlo & 7) << 3;
    _Float16* gb = G_h + (size_t)j * 3072;
    for (int tile = wv; tile < 9; tile += 8) {
      int mt = tile / 3, kt = tile % 3;
      f32x4 acc = (f32x4)0.f;
#pragma unroll
      for (int ks = 0; ks < 16; ++ks) {
        int kk = ks * 32 + koff;
        int ch = kk >> 7, din = (kk & 127) ^ sw;
        f16x8 af = *(const f16x8*)(capT + ch * 6144 + (mt * 16 + rlo) * 128 + din);
        f16x8 bf = *(const f16x8*)(capT + ch * 6144 + (kt * 16 + rlo) * 128 + din);
        acc = __builtin_amdgcn_mfma_f32_16x16x32_f16(af, bf, acc, 0, 0, 0);
      }
#pragma unroll
      for (int r = 0; r < 4; ++r) {
        int w = mt * 16 + hi * 4 + r, k = kt * 16 + rlo;
        float val = (w < W && k < W) ? acc[r] : 0.f;
        gb[w * 64 + k] = (_Float16)val;
      }
    }
    // zero G cols 48..63 (K-tail read against E tail garbage -> must be 0)
    if (t < 96) {
      int w = t >> 1, c8 = 48 + (t & 1) * 8;
      *(f16x8*)(gb + w * 64 + c8) = (f16x8)(_Float16)0.f;
    }
  }
}

// ---------------- k_fused: 256 blocks x 512 thr = 1 block/CU ----------------
// GEMM: capMat(3072x512) x imgMat^T -> 192x256 C-tile/block, BK=64.
// Wave (wm,wn of 2x4): 96x64 output = TWO complete (j,i) pairs in registers.
// Epilogue: R10's proven wave-private path, run twice, zero barriers.
__global__ __launch_bounds__(512, 2) void k_fused(
    const _Float16* __restrict__ img_h, const _Float16* __restrict__ cap_h,
    const int* __restrict__ imgL, const int* __restrict__ capL,
    const float* __restrict__ n1g, const _Float16* __restrict__ G_h,
    float* __restrict__ S) {
  __shared__ __align__(16) char buf[114688];  // 2 x 56KB K-tile dbuf; Es aliased later

  int t = threadIdx.x;
  int lane = t & 63, wv = t >> 6;
  int rlo = lane & 15, hi = lane >> 4;
  int koff = hi * 8;
  int sw = (rlo & 7) << 3;
  int wm = wv >> 2, wn = wv & 3;  // 2 x 4 wave grid

  int bid = blockIdx.x;
  int xcd = bid & 7, s0 = bid >> 3;
  int bj = (xcd & 3) * 4 + (s0 & 3);   // M-tile in [0,16): 4 cap-quads per XCD
  int bi = (xcd >> 2) * 8 + (s0 >> 2); // N-tile in [0,16): 8 img-quads per XCD

  int i = bi * 4 + wn;       // this wave's image
  int ja = bj * 4 + wm * 2;  // pair a caption; pair b = ja+1
  int iL = imgL[i];
  int cLa = capL[ja], cLb = capL[ja + 1];

  const char* capb = (const char*)cap_h + (size_t)bj * 4 * 49152;
  const char* imgb = (const char*)img_h + (size_t)bi * 4 * 65536;

  // 7 staging descriptors/wave: 56 x 1KB segs per K-tile (A 24KB | B 32KB)
  const char* bsrc[7];
  int cstr[7], mdst[7];
#pragma unroll
  for (int s = 0; s < 7; ++s) {
    int m = s * 8 + wv;
    if (m < 24) {
      bsrc[s] = capb + (m / 6) * 49152 + (m % 6) * 1024 + lane * 16;
      cstr[s] = 6144;
    } else {
      int e = m - 24;
      bsrc[s] = imgb + (e >> 3) * 65536 + (e & 7) * 1024 + lane * 16;
      cstr[s] = 8192;
    }
    mdst[s] = m * 1024;
  }

  f32x4 acc[6][4];
#pragma unroll
  for (int mt = 0; mt < 6; ++mt)
#pragma unroll
    for (int nt = 0; nt < 4; ++nt) acc[mt][nt] = (f32x4)0.f;

  // prologue: stage K-tile 0 (7 gll in flight)
#pragma unroll
  for (int s = 0; s < 7; ++s) gll16(bsrc[s], buf + mdst[s]);

  // ---- K-loop: counted-vmcnt two-barrier pipeline, 8 K-tiles ----
#pragma unroll
  for (int c = 0; c < 8; ++c) {
    if (c < 7) {
      char* db = buf + ((c + 1) & 1) * 57344;
#pragma unroll
      for (int s = 0; s < 7; ++s) gll16(bsrc[s] + (c + 1) * cstr[s], db + mdst[s]);
      asm volatile("s_waitcnt vmcnt(7)" ::: "memory");  // tile-c landed; c+1 in flight
    } else {
      asm volatile("s_waitcnt vmcnt(0)" ::: "memory");
    }
    __builtin_amdgcn_s_barrier();
    __builtin_amdgcn_sched_barrier(0);
    const char* cb = buf + (c & 1) * 57344;
    const _Float16* Al = (const _Float16*)cb;                        // 4 x [48][64]
    const _Float16* Bl = (const _Float16*)(cb + 24576) + wn * 4096;  // my i: [64][64]
#pragma unroll
    for (int ks = 0; ks < 2; ++ks) {
      int col = (ks * 32 + koff) ^ sw;
      f16x8 bf[4], af[6];
#pragma unroll
      for (int nt = 0; nt < 4; ++nt) bf[nt] = *(const f16x8*)(Bl + (nt * 16 + rlo) * 64 + col);
#pragma unroll
      for (int mt = 0; mt < 6; ++mt) {
        int blk = wm * 2 + (mt >= 3 ? 1 : 0);
        int w = (mt >= 3 ? mt - 3 : mt) * 16 + rlo;
        af[mt] = *(const f16x8*)(Al + blk * 3072 + w * 64 + col);
      }
      __builtin_amdgcn_s_setprio(1);
#pragma unroll
      for (int mt = 0; mt < 6; ++mt)
#pragma unroll
        for (int nt = 0; nt < 4; ++nt)
          acc[mt][nt] = __builtin_amdgcn_mfma_f32_16x16x32_f16(af[mt], bf[nt], acc[mt][nt], 0, 0, 0);
      __builtin_amdgcn_s_setprio(0);
    }
    __builtin_amdgcn_sched_barrier(0);
    __builtin_amdgcn_s_barrier();  // reads of buf[c&1] done -> c+2 may overwrite
  }

  // ---- epilogue: wave-private, zero barriers, run per pair ----
  _Float16* Ew = (_Float16*)(buf + wv * 7168);  // [64][ESTR=56] halves
  float n1lane = n1g[i * F + lane];

#pragma unroll
  for (int p = 0; p < 2; ++p) {
    int j = ja + p;
    int cL = p ? cLb : cLa;
    int mb = p * 3;

    // rnorm: rinv per w from sum_f leaky(A)^2 (f-masked)
    float rinv[3][4];
#pragma unroll
    for (int mt = 0; mt < 3; ++mt)
#pragma unroll
      for (int r = 0; r < 4; ++r) {
        float s = 0.f;
#pragma unroll
        for (int nt = 0; nt < 4; ++nt) {
          float a = acc[mb + mt][nt][r];
          float l = a > 0.f ? a : 0.1f * a;
          s += ((nt * 16 + rlo) < iL) ? l * l : 0.f;
        }
#pragma unroll
        for (int d = 1; d < 16; d <<= 1) s += __shfl_xor(s, d);
        rinv[mt][r] = 1.f / (sqrtf(s) + 1e-8f);
      }

    // fused softmax (logits in [-9,9] -> no max pass) + sn + Es write
    float sn[4] = {0.f, 0.f, 0.f, 0.f};
#pragma unroll
    for (int mt = 0; mt < 3; ++mt)
#pragma unroll
      for (int nt = 0; nt < 4; ++nt) {
        f16x4 ev;
#pragma unroll
        for (int r = 0; r < 4; ++r) {
          int w = mt * 16 + hi * 4 + r;
          float a = acc[mb + mt][nt][r];
          float l = a > 0.f ? a : 0.1f * a;
          float e = (w < cL) ? __expf(LSM * l * rinv[mt][r]) : 0.f;
          sn[nt] = fmaf(e, a, sn[nt]);
          ev[r] = (_Float16)e;
        }
        *(f16x4*)(Ew + (nt * 16 + rlo) * ESTR + mt * 16 + hi * 4) = ev;
      }
#pragma unroll
    for (int nt = 0; nt < 4; ++nt) {
      sn[nt] += __shfl_xor(sn[nt], 16);
      sn[nt] += __shfl_xor(sn[nt], 32);
    }

    // P = E*G (24 MFMA; E K-tail (finite staged fp16) x G zero-cols = 0)
    const _Float16* gB = G_h + (size_t)j * 3072 + rlo * 64 + koff;
    f32x4 P[4][3];
#pragma unroll
    for (int mtl = 0; mtl < 4; ++mtl)
#pragma unroll
      for (int ntl = 0; ntl < 3; ++ntl) P[mtl][ntl] = (f32x4)0.f;
#pragma unroll
    for (int ks2 = 0; ks2 < 2; ++ks2) {
      int kk2 = ks2 * 32;
      f16x8 bfg[3];
#pragma unroll
      for (int ntl = 0; ntl < 3; ++ntl) bfg[ntl] = *(const f16x8*)(gB + ntl * 1024 + kk2);
#pragma unroll
      for (int mtl = 0; mtl < 4; ++mtl) {
        f16x8 af = *(const f16x8*)(Ew + (mtl * 16 + rlo) * ESTR + kk2 + koff);
#pragma unroll
        for (int ntl = 0; ntl < 3; ++ntl)
          P[mtl][ntl] = __builtin_amdgcn_mfma_f32_16x16x32_f16(af, bfg[ntl], P[mtl][ntl], 0, 0, 0);
      }
    }

    // n2^2 per f; sim; LSE over f; one store per wave per pair
    float ef = 0.f;
#pragma unroll
    for (int mtl = 0; mtl < 4; ++mtl) {
#pragma unroll
      for (int rr = 0; rr < 4; ++rr) {
        int fm = mtl * 16 + hi * 4 + rr;
        float n2s = 0.f;
#pragma unroll
        for (int ntl = 0; ntl < 3; ++ntl) {
          float evv = (float)Ew[fm * ESTR + ntl * 16 + rlo];
          n2s = fmaf(P[mtl][ntl][rr], evv, n2s);
        }
#pragma unroll
        for (int d = 1; d < 16; d <<= 1) n2s += __shfl_xor(n2s, d);
        float nm = __shfl(sn[mtl], hi * 4 + rr);
        float n1v = __shfl(n1lane, fm);
        float denom = n1v * sqrtf(fmaxf(n2s, 0.f));
        float sim = nm / fmaxf(denom, 1e-20f);
        ef += (fm < iL) ? __expf(LLSE * sim) : 0.f;
      }
    }
    ef += __shfl_xor(ef, 16);
    ef += __shfl_xor(ef, 32);
    if (lane == 0) S[(j << 6) + i] = __logf(ef) * (1.f / LLSE);
  }
}

// ---------------- k_loss ----------------
__global__ void k_loss(const float* __restrict__ S, float* __restrict__ out) {
  __shared__ float red[128];
  int t = threadIdx.x;
  float m = -1e30f;
  if (t < 64) {
    int a = t;
    float da = S[a * N + a];
    for (int b = 0; b < N; ++b)
      if (b != a) m = fmaxf(m, MARG + S[a * N + b] - da);
  } else {
    int b = t - 64;
    float db = S[b * N + b];
    for (int a = 0; a < N; ++a)
      if (a != b) m = fmaxf(m, MARG + S[a * N + b] - db);
  }
  red[t] = fmaxf(m, 0.f);
  __syncthreads();
  if (t < 64) {
    float v = red[t] + red[t + 64];
#pragma unroll
    for (int off = 1; off < 64; off <<= 1) v += __shfl_xor(v, off);
    if (t == 0) *out = v;
  }
}

extern "C" void kernel_launch(void* const* d_in, const int* in_sizes, int n_in,
                              void* d_out, int out_size, void* d_ws, size_t ws_size,
                              hipStream_t stream) {
  const float* img = (const float*)d_in[0];
  const float* cap = (const float*)d_in[1];
  const int* imgL = (const int*)d_in[2];
  const int* capL = (const int*)d_in[3];

  char* wsb = (char*)d_ws;
  float* n1 = (float*)wsb;                                       // 16 KB
  float* S = (float*)(wsb + 16384);                              // 16 KB
  _Float16* img_h = (_Float16*)(wsb + 32768);                    // 4 MB
  _Float16* cap_h = (_Float16*)(wsb + 32768 + 4194304);          // 3 MB
  _Float16* G_h = (_Float16*)(wsb + 32768 + 4194304 + 3145728);  // 384 KB

  k_pre<<<320, 512, 0, stream>>>(img, cap, img_h, cap_h, G_h, n1);
  k_fused<<<256, 512, 0, stream>>>(img_h, cap_h, imgL, capL, n1, G_h, S);
  k_loss<<<1, 128, 0, stream>>>(S, (float*)d_out);
}

// Round 13
// 51.078 us; speedup vs baseline: 1.2080x; 1.0586x over previous
//
#include <hip/hip_runtime.h>
#include <math.h>

#define N 64
#define F 64
#define W 40
#define D 512
#define LSM 9.0f
#define LLSE 6.0f
#define MARG 0.2f
#define ESTR 56  // Es row stride in halves

typedef _Float16 f16x8 __attribute__((ext_vector_type(8)));
typedef _Float16 f16x4 __attribute__((ext_vector_type(4)));
typedef float f32x4 __attribute__((ext_vector_type(4)));

__device__ inline void gll16(const void* g, void* l) {
  __builtin_amdgcn_global_load_lds(
      (const __attribute__((address_space(1))) unsigned int*)g,
      (__attribute__((address_space(3))) unsigned int*)l, 16, 0, 0);
}

// layouts (halves), K-chunked (8 chunks of 64) + XOR swizzle baked in:
//  img_h per i: [ch8][f64][64],  halfidx ^ ((f&7)<<3)               (32768)
//  cap_h per j: [ch8][w48][64], halfidx ^ ((w&7)<<3), rows 40..47=0 (24576)
//  G_h  per j: [w48][64] linear, zero outside 40 rows/48 cols       (3072)

// ---------------- k_pre: grid 320 x 512 (unchanged, proven) ----------------
__global__ __launch_bounds__(512) void k_pre(
    const float* __restrict__ img, const float* __restrict__ cap,
    _Float16* __restrict__ img_h, _Float16* __restrict__ cap_h,
    _Float16* __restrict__ G_h, float* __restrict__ n1) {
  __shared__ __align__(16) _Float16 capT[4 * 48 * 128];  // 48 KB (cap blocks only)
  int t = threadIdx.x;
  int b = blockIdx.x;
  if (b < 256) {
    int i = b >> 2;
    int f = ((b & 3) << 4) + (t >> 5);
    int q = t & 31;  // 16 halves per thread
    const float* row = img + ((size_t)i * F + f) * D + q * 16;
    _Float16* dsti = img_h + (size_t)i * 32768;
    int fsw = (f & 7) << 3;
    float s = 0.f;
    int d0 = q * 16;
    int ch = d0 >> 6, din = d0 & 63;
#pragma unroll
    for (int k = 0; k < 2; ++k) {
      float4 u = *(const float4*)(row + k * 8);
      float4 v = *(const float4*)(row + k * 8 + 4);
      s += u.x * u.x + u.y * u.y + u.z * u.z + u.w * u.w;
      s += v.x * v.x + v.y * v.y + v.z * v.z + v.w * v.w;
      f16x8 h;
      h[0] = (_Float16)u.x; h[1] = (_Float16)u.y; h[2] = (_Float16)u.z; h[3] = (_Float16)u.w;
      h[4] = (_Float16)v.x; h[5] = (_Float16)v.y; h[6] = (_Float16)v.z; h[7] = (_Float16)v.w;
      *(f16x8*)(dsti + ch * 4096 + f * 64 + ((din + k * 8) ^ fsw)) = h;
    }
    s += __shfl_xor(s, 1);
    s += __shfl_xor(s, 2);
    s += __shfl_xor(s, 4);
    s += __shfl_xor(s, 8);
    s += __shfl_xor(s, 16);
    if (q == 0) n1[i * F + f] = sqrtf(s);
  } else {
    int j = b - 256;
    int lane = t & 63, wv = t >> 6;
    const float* src = cap + (size_t)j * W * D;
    _Float16* dst = cap_h + (size_t)j * 24576;
#pragma unroll
    for (int k = 0; k < 6; ++k) {
      int slot = t + k * 512;  // 48 rows x 64 col-chunks
      int w = slot >> 6, d = (slot & 63) * 8;
      float4 u = {0.f, 0.f, 0.f, 0.f}, v = {0.f, 0.f, 0.f, 0.f};
      if (w < W) {
        u = *(const float4*)(src + (size_t)w * D + d);
        v = *(const float4*)(src + (size_t)w * D + d + 4);
      }
      f16x8 h;
      h[0] = (_Float16)u.x; h[1] = (_Float16)u.y; h[2] = (_Float16)u.z; h[3] = (_Float16)u.w;
      h[4] = (_Float16)v.x; h[5] = (_Float16)v.y; h[6] = (_Float16)v.z; h[7] = (_Float16)v.w;
      int wsw = (w & 7) << 3;
      int ch2 = d >> 6, din2 = d & 63;
      *(f16x8*)(dst + ch2 * 3072 + w * 64 + (din2 ^ wsw)) = h;
      int chO = d >> 7, dinO = d & 127;
      *(f16x8*)(capT + chO * 6144 + w * 128 + (dinO ^ wsw)) = h;
    }
    __syncthreads();
    int lane2 = t & 63;
    int rlo = lane2 & 15, hi = lane2 >> 4;
    int koff = hi * 8, sw = (rlo & 7) << 3;
    _Float16* gb = G_h + (size_t)j * 3072;
    for (int tile = wv; tile < 9; tile += 8) {
      int mt = tile / 3, kt = tile % 3;
      f32x4 acc = (f32x4)0.f;
#pragma unroll
      for (int ks = 0; ks < 16; ++ks) {
        int kk = ks * 32 + koff;
        int ch = kk >> 7, din = (kk & 127) ^ sw;
        f16x8 af = *(const f16x8*)(capT + ch * 6144 + (mt * 16 + rlo) * 128 + din);
        f16x8 bf = *(const f16x8*)(capT + ch * 6144 + (kt * 16 + rlo) * 128 + din);
        acc = __builtin_amdgcn_mfma_f32_16x16x32_f16(af, bf, acc, 0, 0, 0);
      }
#pragma unroll
      for (int r = 0; r < 4; ++r) {
        int w = mt * 16 + hi * 4 + r, k = kt * 16 + rlo;
        float val = (w < W && k < W) ? acc[r] : 0.f;
        gb[w * 64 + k] = (_Float16)val;
      }
    }
    // zero G cols 48..63 (K-tail of P2 reads E garbage -> A=G cols must be 0)
    if (t < 96) {
      int w = t >> 1, c8 = 48 + (t & 1) * 8;
      *(f16x8*)(gb + w * 64 + c8) = (f16x8)(_Float16)0.f;
    }
  }
}

// ---------------- k_fused: 256 blocks x 512 thr = 1 block/CU ----------------
// GEMM: capMat(3072x512) x imgMat^T -> 192x256 C-tile/block, BK=64.
// Wave (wm,wn of 2x4): 96x64 output = TWO complete (j,i) pairs in registers.
// Epilogue v2: P2 = G x E^T puts f on lanes; tail reads E from REGISTERS
// (the lane that needs E[f][w] is the lane that computed it), 4 tails/lane.
__global__ __launch_bounds__(512, 2) void k_fused(
    const _Float16* __restrict__ img_h, const _Float16* __restrict__ cap_h,
    const int* __restrict__ imgL, const int* __restrict__ capL,
    const float* __restrict__ n1g, const _Float16* __restrict__ G_h,
    float* __restrict__ S) {
  __shared__ __align__(16) char buf[114688];  // 2 x 56KB K-tile dbuf; Es aliased later

  int t = threadIdx.x;
  int lane = t & 63, wv = t >> 6;
  int rlo = lane & 15, hi = lane >> 4;
  int koff = hi * 8;
  int sw = (rlo & 7) << 3;
  int wm = wv >> 2, wn = wv & 3;  // 2 x 4 wave grid

  int bid = blockIdx.x;
  int xcd = bid & 7, s0 = bid >> 3;
  int bj = (xcd & 3) * 4 + (s0 & 3);   // M-tile in [0,16)
  int bi = (xcd >> 2) * 8 + (s0 >> 2); // N-tile in [0,16)

  int i = bi * 4 + wn;       // this wave's image
  int ja = bj * 4 + wm * 2;  // pair a caption; pair b = ja+1
  int iL = imgL[i];
  int cLa = capL[ja], cLb = capL[ja + 1];

  const char* capb = (const char*)cap_h + (size_t)bj * 4 * 49152;
  const char* imgb = (const char*)img_h + (size_t)bi * 4 * 65536;

  // 7 staging descriptors/wave: 56 x 1KB segs per K-tile (A 24KB | B 32KB)
  const char* bsrc[7];
  int cstr[7], mdst[7];
#pragma unroll
  for (int s = 0; s < 7; ++s) {
    int m = s * 8 + wv;
    if (m < 24) {
      bsrc[s] = capb + (m / 6) * 49152 + (m % 6) * 1024 + lane * 16;
      cstr[s] = 6144;
    } else {
      int e = m - 24;
      bsrc[s] = imgb + (e >> 3) * 65536 + (e & 7) * 1024 + lane * 16;
      cstr[s] = 8192;
    }
    mdst[s] = m * 1024;
  }

  f32x4 acc[6][4];
#pragma unroll
  for (int mt = 0; mt < 6; ++mt)
#pragma unroll
    for (int nt = 0; nt < 4; ++nt) acc[mt][nt] = (f32x4)0.f;

  // prologue: stage K-tile 0 (7 gll in flight)
#pragma unroll
  for (int s = 0; s < 7; ++s) gll16(bsrc[s], buf + mdst[s]);

  // ---- K-loop: counted-vmcnt two-barrier pipeline, 8 K-tiles ----
#pragma unroll
  for (int c = 0; c < 8; ++c) {
    if (c < 7) {
      char* db = buf + ((c + 1) & 1) * 57344;
#pragma unroll
      for (int s = 0; s < 7; ++s) gll16(bsrc[s] + (c + 1) * cstr[s], db + mdst[s]);
      asm volatile("s_waitcnt vmcnt(7)" ::: "memory");  // tile-c landed; c+1 in flight
    } else {
      asm volatile("s_waitcnt vmcnt(0)" ::: "memory");
    }
    __builtin_amdgcn_s_barrier();
    __builtin_amdgcn_sched_barrier(0);
    const char* cb = buf + (c & 1) * 57344;
    const _Float16* Al = (const _Float16*)cb;                        // 4 x [48][64]
    const _Float16* Bl = (const _Float16*)(cb + 24576) + wn * 4096;  // my i: [64][64]
#pragma unroll
    for (int ks = 0; ks < 2; ++ks) {
      int col = (ks * 32 + koff) ^ sw;
      f16x8 bf[4], af[6];
#pragma unroll
      for (int nt = 0; nt < 4; ++nt) bf[nt] = *(const f16x8*)(Bl + (nt * 16 + rlo) * 64 + col);
#pragma unroll
      for (int mt = 0; mt < 6; ++mt) {
        int blk = wm * 2 + (mt >= 3 ? 1 : 0);
        int w = (mt >= 3 ? mt - 3 : mt) * 16 + rlo;
        af[mt] = *(const f16x8*)(Al + blk * 3072 + w * 64 + col);
      }
      __builtin_amdgcn_s_setprio(1);
#pragma unroll
      for (int mt = 0; mt < 6; ++mt)
#pragma unroll
        for (int nt = 0; nt < 4; ++nt)
          acc[mt][nt] = __builtin_amdgcn_mfma_f32_16x16x32_f16(af[mt], bf[nt], acc[mt][nt], 0, 0, 0);
      __builtin_amdgcn_s_setprio(0);
    }
    __builtin_amdgcn_sched_barrier(0);
    __builtin_amdgcn_s_barrier();  // reads of buf[c&1] done -> c+2 may overwrite
  }

  // ---- epilogue v2: wave-private, zero barriers, per pair ----
  _Float16* Ew = (_Float16*)(buf + wv * 7168);  // [64][ESTR=56] halves
  float n1lane = n1g[i * F + lane];

#pragma unroll
  for (int p = 0; p < 2; ++p) {
    int j = ja + p;
    int cL = p ? cLb : cLa;
    int mb = p * 3;

    // rnorm: rinv per w from sum_f leaky(A)^2 (f-masked)
    float rinv[3][4];
#pragma unroll
    for (int mt = 0; mt < 3; ++mt)
#pragma unroll
      for (int r = 0; r < 4; ++r) {
        float s = 0.f;
#pragma unroll
        for (int nt = 0; nt < 4; ++nt) {
          float a = acc[mb + mt][nt][r];
          float l = a > 0.f ? a : 0.1f * a;
          s += ((nt * 16 + rlo) < iL) ? l * l : 0.f;
        }
#pragma unroll
        for (int d = 1; d < 16; d <<= 1) s += __shfl_xor(s, d);
        rinv[mt][r] = 1.f / (sqrtf(s) + 1e-8f);
      }

    // fused softmax (logits in [-9,9] -> no max pass) + sn + E to regs + Es write
    float sn[4] = {0.f, 0.f, 0.f, 0.f};
    f16x4 evs[3][4];  // lane-owned E[f = nt*16+rlo][w = mt*16+hi*4+r]
#pragma unroll
    for (int mt = 0; mt < 3; ++mt)
#pragma unroll
      for (int nt = 0; nt < 4; ++nt) {
        f16x4 ev;
#pragma unroll
        for (int r = 0; r < 4; ++r) {
          int w = mt * 16 + hi * 4 + r;
          float a = acc[mb + mt][nt][r];
          float l = a > 0.f ? a : 0.1f * a;
          float e = (w < cL) ? __expf(LSM * l * rinv[mt][r]) : 0.f;
          sn[nt] = fmaf(e, a, sn[nt]);
          ev[r] = (_Float16)e;
        }
        evs[mt][nt] = ev;
        *(f16x4*)(Ew + (nt * 16 + rlo) * ESTR + mt * 16 + hi * 4) = ev;
      }
#pragma unroll
    for (int nt = 0; nt < 4; ++nt) {
      sn[nt] += __shfl_xor(sn[nt], 16);
      sn[nt] += __shfl_xor(sn[nt], 32);
    }

    // P2 = G x E^T (24 MFMA): C[w][f] -> f on lanes (col = rlo)
    const _Float16* gB = G_h + (size_t)j * 3072;
    f32x4 P2[3][4];
#pragma unroll
    for (int wb = 0; wb < 3; ++wb)
#pragma unroll
      for (int fb = 0; fb < 4; ++fb) P2[wb][fb] = (f32x4)0.f;
#pragma unroll
    for (int ks2 = 0; ks2 < 2; ++ks2) {
      int kk2 = ks2 * 32 + koff;
      f16x8 ga[3], eb[4];
#pragma unroll
      for (int wb = 0; wb < 3; ++wb)
        ga[wb] = *(const f16x8*)(gB + (wb * 16 + rlo) * 64 + kk2);
#pragma unroll
      for (int fb = 0; fb < 4; ++fb)
        eb[fb] = *(const f16x8*)(Ew + (fb * 16 + rlo) * ESTR + kk2);
#pragma unroll
      for (int wb = 0; wb < 3; ++wb)
#pragma unroll
        for (int fb = 0; fb < 4; ++fb)
          P2[wb][fb] = __builtin_amdgcn_mfma_f32_16x16x32_f16(ga[wb], eb[fb], P2[wb][fb], 0, 0, 0);
    }

    // tail: n2^2[f] = sum_w P2[w][f]*E[f][w] -- E from REGISTERS (same lane),
    // 2 shfl per f-block; sim+exp once per (lane, fb); ef uniform across hi.
    float ef = 0.f;
#pragma unroll
    for (int fb = 0; fb < 4; ++fb) {
      int f = fb * 16 + rlo;
      float n2s = 0.f;
#pragma unroll
      for (int wb = 0; wb < 3; ++wb)
#pragma unroll
        for (int r = 0; r < 4; ++r)
          n2s = fmaf(P2[wb][fb][r], (float)evs[wb][fb][r], n2s);
      n2s += __shfl_xor(n2s, 16);
      n2s += __shfl_xor(n2s, 32);
      float nm = sn[fb];
      float n1v = __shfl(n1lane, f);
      float denom = n1v * sqrtf(fmaxf(n2s, 0.f));
      float sim = nm / fmaxf(denom, 1e-20f);
      ef += (f < iL) ? __expf(LLSE * sim) : 0.f;
    }
    ef += __shfl_xor(ef, 1);
    ef += __shfl_xor(ef, 2);
    ef += __shfl_xor(ef, 4);
    ef += __shfl_xor(ef, 8);
    if (lane == 0) S[(j << 6) + i] = __logf(ef) * (1.f / LLSE);
  }
}

// ---------------- k_loss ----------------
__global__ void k_loss(const float* __restrict__ S, float* __restrict__ out) {
  __shared__ float red[128];
  int t = threadIdx.x;
  float m = -1e30f;
  if (t < 64) {
    int a = t;
    float da = S[a * N + a];
    for (int b = 0; b < N; ++b)
      if (b != a) m = fmaxf(m, MARG + S[a * N + b] - da);
  } else {
    int b = t - 64;
    float db = S[b * N + b];
    for (int a = 0; a < N; ++a)
      if (a != b) m = fmaxf(m, MARG + S[a * N + b] - db);
  }
  red[t] = fmaxf(m, 0.f);
  __syncthreads();
  if (t < 64) {
    float v = red[t] + red[t + 64];
#pragma unroll
    for (int off = 1; off < 64; off <<= 1) v += __shfl_xor(v, off);
    if (t == 0) *out = v;
  }
}

extern "C" void kernel_launch(void* const* d_in, const int* in_sizes, int n_in,
                              void* d_out, int out_size, void* d_ws, size_t ws_size,
                              hipStream_t stream) {
  const float* img = (const float*)d_in[0];
  const float* cap = (const float*)d_in[1];
  const int* imgL = (const int*)d_in[2];
  const int* capL = (const int*)d_in[3];

  char* wsb = (char*)d_ws;
  float* n1 = (float*)wsb;                                       // 16 KB
  float* S = (float*)(wsb + 16384);                              // 16 KB
  _Float16* img_h = (_Float16*)(wsb + 32768);                    // 4 MB
  _Float16* cap_h = (_Float16*)(wsb + 32768 + 4194304);          // 3 MB
  _Float16* G_h = (_Float16*)(wsb + 32768 + 4194304 + 3145728);  // 384 KB

  k_pre<<<320, 512, 0, stream>>>(img, cap, img_h, cap_h, G_h, n1);
  k_fused<<<256, 512, 0, stream>>>(img_h, cap_h, imgL, capL, n1, G_h, S);
  k_loss<<<1, 128, 0, stream>>>(S, (float*)d_out);
}